// Round 6
// baseline (959.740 us; speedup 1.0000x reference)
//
#include <hip/hip_runtime.h>
#include <hip/hip_bf16.h>

typedef _Float16 half8_t __attribute__((ext_vector_type(8)));
typedef _Float16 half4_t __attribute__((ext_vector_type(4)));
typedef _Float16 half2_t __attribute__((ext_vector_type(2)));
typedef float float4_t __attribute__((ext_vector_type(4)));
typedef unsigned int uint2_t __attribute__((ext_vector_type(2)));

#define TT 1024
#define BB 128
#define EE 128
#define HH 128
#define NTAG 64
#define ASTR 144  // [batch][hu] LDS panel stride (f16) — R6-proven for the b128 read pattern

__device__ __forceinline__ float fast_exp(float x) {
  return __builtin_amdgcn_exp2f(x * 1.44269504088896f);
}
// LDS-only barrier: does NOT drain vmcnt -> global loads/stores stay in flight.
__device__ __forceinline__ void lds_barrier() {
  asm volatile("s_waitcnt lgkmcnt(0)\n\ts_barrier" ::: "memory");
}
// Single-wave LDS write->read fence.
__device__ __forceinline__ void lds_fence() {
  asm volatile("s_waitcnt lgkmcnt(0)" ::: "memory");
}
__device__ __forceinline__ half2_t cvt_pk(float a, float b) {
  return __builtin_bit_cast(half2_t, __builtin_amdgcn_cvt_pkrtz(a, b));
}
__device__ __forceinline__ half2_t h2bc(float v) {
  _Float16 h = (_Float16)v;
  half2_t r; r[0] = h; r[1] = h;
  return r;
}
__device__ __forceinline__ half8_t h8bc(float v) {
  _Float16 h = (_Float16)v;
  half8_t r;
#pragma unroll
  for (int i = 0; i < 8; ++i) r[i] = h;
  return r;
}
// max over the 4 quads (lane bits 4,5) for each n16 column — pure VALU (permlane swaps)
__device__ __forceinline__ float quad_max4(float v) {
  unsigned a = __builtin_bit_cast(unsigned, v);
  uint2_t r = __builtin_amdgcn_permlane32_swap(a, a, false, false);
  float m = fmaxf(__builtin_bit_cast(float, r[0]), __builtin_bit_cast(float, r[1]));
  unsigned b = __builtin_bit_cast(unsigned, m);
  uint2_t s = __builtin_amdgcn_permlane16_swap(b, b, false, false);
  return fmaxf(__builtin_bit_cast(float, s[0]), __builtin_bit_cast(float, s[1]));
}
// deg-5 odd tanh poly (fit at 1, 1.6; clamp +-1.6): 6 pk instrs
__device__ __forceinline__ half2_t tanh6(half2_t x) {
  half2_t y = __builtin_elementwise_min(__builtin_elementwise_max(x, h2bc(-1.6f)), h2bc(1.6f));
  half2_t u = y * y;
  half2_t p = u * h2bc(0.04667f) + h2bc(-0.28507f);
  p = u * p + h2bc(1.0f);
  return y * p;
}
// sigmoid, x/2 folded into coefficients: 6 pk instrs
__device__ __forceinline__ half2_t sig6(half2_t x) {
  half2_t y = __builtin_elementwise_min(__builtin_elementwise_max(x, h2bc(-3.2f)), h2bc(3.2f));
  half2_t u = y * y;
  half2_t q = u * h2bc(0.00072921875f) + h2bc(-0.017816875f);
  q = u * q + h2bc(0.25f);
  return y * q + h2bc(0.5f);
}

// ---------------------------------------------------------------- init: zero LSTM state
__global__ __launch_bounds__(256) void init_kernel(float4_t* __restrict__ p) {
  p[blockIdx.x * 256 + threadIdx.x] = (float4_t){0.f, 0.f, 0.f, 0.f};
}

// ---------------------------------------------------------------- embed: x[t*B+b][e] f16
__global__ __launch_bounds__(256) void embed_kernel(const int* __restrict__ kmers,
                                                    const float* __restrict__ emb,
                                                    half4_t* __restrict__ x) {
  const int g = blockIdx.x * 256 + threadIdx.x;
  const int row = g >> 5, seg = g & 31;
  const int km = kmers[row];
  const float4_t v = ((const float4_t*)(emb + (size_t)km * EE))[seg];
  half4_t o;
  o[0] = (_Float16)v[0]; o[1] = (_Float16)v[1];
  o[2] = (_Float16)v[2]; o[3] = (_Float16)v[3];
  x[(size_t)row * 32 + seg] = o;
}

// ---------------------------------------------------------------- xg body (device)
// Orientation: A = W_ih (regs), B = x^T (b128 global loads), C rows=hu-part, col=batch.
__device__ __forceinline__ void xg_body(
    int wg, const _Float16* __restrict__ x,
    const float* __restrict__ w_ih_f, const float* __restrict__ b_ih_f, const float* __restrict__ b_hh_f,
    const float* __restrict__ w_ih_b, const float* __restrict__ b_ih_b, const float* __restrict__ b_hh_b,
    _Float16* __restrict__ xgbuf, int s, int Tseg) {
  const int nt = Tseg >> 4;
  const int dir = wg / (8 * nt);
  const int rem = wg - dir * 8 * nt;
  const int chunk = rem / nt;
  const int tb = rem - chunk * nt;
  const int tid = threadIdx.x;
  const int wave = tid >> 6, lane = tid & 63;
  const int n16 = lane & 15, quad = lane >> 4;

  const float* wih = dir ? w_ih_b : w_ih_f;
  const float* bih = dir ? b_ih_b : b_ih_f;
  const float* bhh = dir ? b_hh_b : b_hh_f;

  half8_t wf[4][4];
#pragma unroll
  for (int g = 0; g < 4; ++g) {
    const int row = g * HH + wave * 16 + n16;
#pragma unroll
    for (int kf = 0; kf < 4; ++kf) {
      const float* src = wih + row * EE + kf * 32 + quad * 8;
#pragma unroll
      for (int i = 0; i < 8; ++i) wf[g][kf][i] = (_Float16)src[i];
    }
  }
  float4_t bias4[4];
#pragma unroll
  for (int g = 0; g < 4; ++g) {
    const int row = g * HH + wave * 16 + quad * 4;
    const float4_t bi = *(const float4_t*)(bih + row);
    const float4_t bh = *(const float4_t*)(bhh + row);
    bias4[g] = bi + bh;
  }

  const int l0 = tb * 16;
  half8_t xb[4];
  {
    const int te = dir ? (TT - 1 - (s * Tseg + l0)) : (s * Tseg + l0);
#pragma unroll
    for (int kf = 0; kf < 4; ++kf)
      xb[kf] = *(const half8_t*)(x + ((size_t)te * BB + chunk * 16 + n16) * EE + kf * 32 + quad * 8);
  }
  for (int u = 0; u < 16; ++u) {
    const int l = l0 + u;
    half8_t xn[4] = {};
    if (u < 15) {
      const int tn = dir ? (TT - 1 - (s * Tseg + l + 1)) : (s * Tseg + l + 1);
#pragma unroll
      for (int kf = 0; kf < 4; ++kf)
        xn[kf] = *(const half8_t*)(x + ((size_t)tn * BB + chunk * 16 + n16) * EE + kf * 32 + quad * 8);
    }
    float4_t acc[4];
#pragma unroll
    for (int g = 0; g < 4; ++g) acc[g] = bias4[g];
#pragma unroll
    for (int kf = 0; kf < 4; ++kf)
#pragma unroll
      for (int g = 0; g < 4; ++g)
        acc[g] = __builtin_amdgcn_mfma_f32_16x16x32_f16(wf[g][kf], xb[kf], acc[g], 0, 0, 0);
    half8_t ho0, ho1;
#pragma unroll
    for (int r = 0; r < 4; ++r) {
      ho0[r] = (_Float16)acc[0][r];
      ho0[4 + r] = (_Float16)acc[1][r];
      ho1[r] = (_Float16)acc[2][r];
      ho1[4 + r] = (_Float16)acc[3][r];
    }
    _Float16* ob = xgbuf + (size_t)dir * Tseg * 65536 + (size_t)l * 65536 + chunk * 8192 +
                   wave * 1024 + lane * 16;
    *(half8_t*)ob = ho0;
    *(half8_t*)(ob + 8) = ho1;
#pragma unroll
    for (int kf = 0; kf < 4; ++kf) xb[kf] = xn[kf];
  }
}

// ---------------------------------------------------------------- standalone xg (first segment)
__global__ __launch_bounds__(512) void xg_kernel(
    const _Float16* __restrict__ x,
    const float* __restrict__ w_ih_f, const float* __restrict__ b_ih_f, const float* __restrict__ b_hh_f,
    const float* __restrict__ w_ih_b, const float* __restrict__ b_ih_b, const float* __restrict__ b_hh_b,
    _Float16* __restrict__ xgbuf, int s, int Tseg) {
  xg_body(blockIdx.x, x, w_ih_f, b_ih_f, b_hh_f, w_ih_b, b_ih_b, b_hh_b, xgbuf, s, Tseg);
}

// ---------------------------------------------------------------- fused: lstm(s) + xg(s+1)
// Blocks 0..15: bidirectional LSTM segment s (serial chain, 16 CUs); blocks 16+: xg(sx) into
// the other double-buffer half (independent, fills idle CUs). 4-deep in-place prefetch ring.
__global__ __launch_bounds__(512, 2) void lstm_xg_kernel(
    const _Float16* __restrict__ xgrd, _Float16* __restrict__ xgwr,
    const _Float16* __restrict__ x,
    const float* __restrict__ w_hh_f, const float* __restrict__ w_hh_b,
    const float* __restrict__ w_ih_f, const float* __restrict__ b_ih_f, const float* __restrict__ b_hh_f,
    const float* __restrict__ w_ih_b, const float* __restrict__ b_ih_b, const float* __restrict__ b_hh_b,
    _Float16* __restrict__ h_cat, _Float16* __restrict__ h_state, float* __restrict__ c_state,
    int s, int sx, int Tseg) {
  __shared__ _Float16 A[2][16 * ASTR];
  if (blockIdx.x >= 16) {
    xg_body(blockIdx.x - 16, x, w_ih_f, b_ih_f, b_hh_f, w_ih_b, b_ih_b, b_hh_b, xgwr, sx, Tseg);
    return;
  }
  const int wg = blockIdx.x;
  const int dir = wg >> 3, chunk = wg & 7;
  const int b0 = chunk * 16;
  const float* w_hh = dir ? w_hh_b : w_hh_f;
  const int tid = threadIdx.x;
  const int wave = tid >> 6, lane = tid & 63;
  const int n16 = lane & 15, quad = lane >> 4;

  half8_t wf[4][4];
#pragma unroll
  for (int g = 0; g < 4; ++g) {
    const int row = g * HH + wave * 16 + n16;
#pragma unroll
    for (int kf = 0; kf < 4; ++kf) {
      const float* src = w_hh + row * HH + kf * 32 + quad * 8;
#pragma unroll
      for (int i = 0; i < 8; ++i) wf[g][kf][i] = (_Float16)src[i];
    }
  }
  const int sidx = ((wg * 8 + wave) * 64 + lane) * 4;
  half4_t h4 = *(const half4_t*)(h_state + sidx);
  float4_t c4 = *(const float4_t*)(c_state + sidx);
  half2_t c2[2];
  c2[0] = cvt_pk(c4[0], c4[1]);
  c2[1] = cvt_pk(c4[2], c4[3]);
  *(half4_t*)(&A[0][n16 * ASTR + wave * 16 + quad * 4]) = h4;  // seed h_{-1}

  const _Float16* xgw =
      xgrd + (size_t)dir * Tseg * 65536 + chunk * 8192 + wave * 1024 + (size_t)lane * 16;
  half4_t hlast = h4;
  const float4_t z4 = {0.f, 0.f, 0.f, 0.f};
  const int te0 = dir ? (TT - 1 - s * Tseg) : (s * Tseg);
  _Float16* gp_run =
      h_cat + ((size_t)te0 * BB + b0 + n16) * 256 + dir * HH + wave * 16 + quad * 4;
  const ptrdiff_t dstep = dir ? -(ptrdiff_t)32768 : (ptrdiff_t)32768;

  half8_t pf0[4], pf1[4];
#pragma unroll
  for (int j = 0; j < 4; ++j) {
    const _Float16* p = xgw + (size_t)j * 65536;
    pf0[j] = *(const half8_t*)p;
    pf1[j] = *(const half8_t*)(p + 8);
  }

#define LSTM_STEP(AB, AN, X0, X1)                                                          \
  {                                                                                        \
    const _Float16* Abp = &AB[0];                                                          \
    _Float16* Anp = &AN[0];                                                                \
    half8_t hb0 = *(const half8_t*)(Abp + n16 * ASTR + 0 * 32 + quad * 8);                 \
    half8_t hb1 = *(const half8_t*)(Abp + n16 * ASTR + 1 * 32 + quad * 8);                 \
    half8_t hb2 = *(const half8_t*)(Abp + n16 * ASTR + 2 * 32 + quad * 8);                 \
    half8_t hb3 = *(const half8_t*)(Abp + n16 * ASTR + 3 * 32 + quad * 8);                 \
    float4_t acc[4];                                                                       \
    _Pragma("unroll") for (int g = 0; g < 4; ++g) {                                        \
      acc[g] = __builtin_amdgcn_mfma_f32_16x16x32_f16(wf[g][0], hb0, z4, 0, 0, 0);         \
    }                                                                                      \
    _Pragma("unroll") for (int g = 0; g < 4; ++g) {                                        \
      acc[g] = __builtin_amdgcn_mfma_f32_16x16x32_f16(wf[g][1], hb1, acc[g], 0, 0, 0);     \
    }                                                                                      \
    _Pragma("unroll") for (int g = 0; g < 4; ++g) {                                        \
      acc[g] = __builtin_amdgcn_mfma_f32_16x16x32_f16(wf[g][2], hb2, acc[g], 0, 0, 0);     \
    }                                                                                      \
    _Pragma("unroll") for (int g = 0; g < 4; ++g) {                                        \
      acc[g] = __builtin_amdgcn_mfma_f32_16x16x32_f16(wf[g][3], hb3, acc[g], 0, 0, 0);     \
    }                                                                                      \
    const half2_t* x0p = (const half2_t*)&X0;                                              \
    const half2_t* x1p = (const half2_t*)&X1;                                              \
    half4_t hstore;                                                                        \
    _Pragma("unroll") for (int p = 0; p < 2; ++p) {                                        \
      const half2_t i_ = sig6(cvt_pk(acc[0][2 * p], acc[0][2 * p + 1]) + x0p[p]);          \
      const half2_t f_ = sig6(cvt_pk(acc[1][2 * p], acc[1][2 * p + 1]) + x0p[2 + p]);      \
      const half2_t g_ = tanh6(cvt_pk(acc[2][2 * p], acc[2][2 * p + 1]) + x1p[p]);         \
      const half2_t o_ = sig6(cvt_pk(acc[3][2 * p], acc[3][2 * p + 1]) + x1p[2 + p]);      \
      c2[p] = f_ * c2[p] + i_ * g_;                                                        \
      const half2_t hh = o_ * tanh6(c2[p]);                                                \
      hstore[2 * p] = hh[0];                                                               \
      hstore[2 * p + 1] = hh[1];                                                           \
    }                                                                                      \
    *(half4_t*)(Anp + n16 * ASTR + wave * 16 + quad * 4) = hstore;                         \
    *(half4_t*)gp_run = hstore;                                                            \
    hlast = hstore;                                                                        \
  }

  for (int il = 0; il < Tseg - 4; il += 4) {
#pragma unroll
    for (int j = 0; j < 4; ++j) {
      lds_barrier();
      if (j & 1) {
        LSTM_STEP(A[1], A[0], pf0[j], pf1[j]);
      } else {
        LSTM_STEP(A[0], A[1], pf0[j], pf1[j]);
      }
      const _Float16* p = xgw + (size_t)(il + j + 4) * 65536;
      pf0[j] = *(const half8_t*)p;
      pf1[j] = *(const half8_t*)(p + 8);
      gp_run += dstep;
    }
  }
#pragma unroll
  for (int j = 0; j < 4; ++j) {
    lds_barrier();
    if (j & 1) {
      LSTM_STEP(A[1], A[0], pf0[j], pf1[j]);
    } else {
      LSTM_STEP(A[0], A[1], pf0[j], pf1[j]);
    }
    gp_run += dstep;
  }
#undef LSTM_STEP

  *(half4_t*)(h_state + sidx) = hlast;
  c4[0] = (float)c2[0][0]; c4[1] = (float)c2[0][1];
  c4[2] = (float)c2[1][0]; c4[3] = (float)c2[1][1];
  *(float4_t*)(c_state + sidx) = c4;
}

// ---------------------------------------------------------------- emissions: em f32 + expem f16
__global__ __launch_bounds__(256) void emis_kernel(const _Float16* __restrict__ h_cat,
                                                   const float* __restrict__ w_proj,
                                                   const float* __restrict__ b_proj,
                                                   float* __restrict__ em,
                                                   _Float16* __restrict__ expem) {
  const int tid = threadIdx.x;
  const int wave = tid >> 6, lane = tid & 63;
  const int n16 = lane & 15, quad = lane >> 4;
  const size_t row0 = (size_t)blockIdx.x * 64 + wave * 16;

  half8_t bf[4][8];
#pragma unroll
  for (int nt = 0; nt < 4; ++nt) {
    const float* wp = w_proj + (nt * 16 + n16) * 256;
#pragma unroll
    for (int kf = 0; kf < 8; ++kf) {
      const int kb = kf * 32 + quad * 8;
#pragma unroll
      for (int i = 0; i < 8; ++i) bf[nt][kf][i] = (_Float16)wp[kb + i];
    }
  }
  float4_t acc[4];
#pragma unroll
  for (int nt = 0; nt < 4; ++nt) {
    const float bv = b_proj[nt * 16 + n16];
    acc[nt] = (float4_t){bv, bv, bv, bv};
  }
#pragma unroll
  for (int kf = 0; kf < 8; ++kf) {
    half8_t af = *(const half8_t*)(h_cat + (row0 + n16) * 256 + kf * 32 + quad * 8);
#pragma unroll
    for (int nt = 0; nt < 4; ++nt)
      acc[nt] = __builtin_amdgcn_mfma_f32_16x16x32_f16(af, bf[nt][kf], acc[nt], 0, 0, 0);
  }
#pragma unroll
  for (int nt = 0; nt < 4; ++nt)
#pragma unroll
    for (int r = 0; r < 4; ++r) {
      const size_t idx = (row0 + quad * 4 + r) * NTAG + nt * 16 + n16;
      em[idx] = acc[nt][r];
      expem[idx] = (_Float16)fast_exp(acc[nt][r]);
    }
}

// ---------------------------------------------------------------- segment-parallel CRF matrices
// 2048 chains (128 batches x 16 segments), 1 wave each: N <- diag(g_t) (E^T N), N init = I,
// t ascending within the segment => N = P_s^T where P_s = prod (E diag g_t). Stored as
// Nbuf[b][s][c][k] = N[k][c] = P_s[c][k] (rows of P contiguous -> coalesced merge reads).
// Same verified CRF core as the vector version, run on 4 column-tiles; wave-uniform rescale
// every 16 steps (log2 in lzbuf). Blocks >= 2048 compute the CRF numerator (hidden here).
__global__ __launch_bounds__(64) void mcrf_kernel(const float* __restrict__ em,
                                                  const _Float16* __restrict__ expem,
                                                  const float* __restrict__ trans,
                                                  const int* __restrict__ tags,
                                                  const float* __restrict__ start_trans,
                                                  const float* __restrict__ end_trans,
                                                  _Float16* __restrict__ Nbuf,
                                                  float* __restrict__ lzbuf,
                                                  float* __restrict__ num) {
  const int lane = threadIdx.x;
  if (blockIdx.x >= 2048) {  // ---------------- numerator (1 wave per batch)
    const int nb = blockIdx.x - 2048;
    const int tg = tags[nb];
    float acc = 0.f;
    for (int t = lane; t < TT; t += 64)
      acc += em[((size_t)t * BB + nb) * NTAG + tg];
#pragma unroll
    for (int off = 32; off > 0; off >>= 1) acc += __shfl_xor(acc, off, 64);
    if (lane == 0)
      num[nb] = start_trans[tg] + end_trans[tg] + 1023.0f * trans[tg * NTAG + tg] + acc;
    return;
  }
  const int n16 = lane & 15, quad = lane >> 4;
  const int b = blockIdx.x >> 4;
  const int s = blockIdx.x & 15;

  // A-frags of E^T scaled 2^-6: A[m][k] = exp(trans[k][m]) * 2^-6
  half8_t efA[4][2];
#pragma unroll
  for (int mt = 0; mt < 4; ++mt)
#pragma unroll
    for (int kf = 0; kf < 2; ++kf)
#pragma unroll
      for (int i = 0; i < 8; ++i) {
        const int m = mt * 16 + n16, k = kf * 32 + quad * 8 + i;
        efA[mt][kf][i] = (_Float16)(fast_exp(trans[k * NTAG + m]) * 0.015625f);
      }

  // N init = I (B-frag layout: pb[tile][kf][i] = N[k][col], k=kf*32+quad*8+i, col=tile*16+n16)
  half8_t pb[4][2];
#pragma unroll
  for (int tile = 0; tile < 4; ++tile)
#pragma unroll
    for (int kf = 0; kf < 2; ++kf)
#pragma unroll
      for (int i = 0; i < 8; ++i) {
        const int k = kf * 32 + quad * 8 + i;
        pb[tile][kf][i] = (_Float16)((k == tile * 16 + n16) ? 1.f : 0.f);
      }

  float lz2 = 0.f;
  const float4_t z4 = {0.f, 0.f, 0.f, 0.f};
  const _Float16* exb = expem + (size_t)b * NTAG;
  const int t0 = s * 64 + 1;
  const int nsteps = (s == 15) ? 63 : 64;

#define MCRF_CORE(PB0, PB1, NB0, NB1)                                                      \
  {                                                                                        \
    float4_t a0 = __builtin_amdgcn_mfma_f32_16x16x32_f16(efA[0][0], PB0, z4, 0, 0, 0);     \
    float4_t a1 = __builtin_amdgcn_mfma_f32_16x16x32_f16(efA[1][0], PB0, z4, 0, 0, 0);     \
    float4_t a2 = __builtin_amdgcn_mfma_f32_16x16x32_f16(efA[2][0], PB0, z4, 0, 0, 0);     \
    float4_t a3 = __builtin_amdgcn_mfma_f32_16x16x32_f16(efA[3][0], PB0, z4, 0, 0, 0);     \
    a0 = __builtin_amdgcn_mfma_f32_16x16x32_f16(efA[0][1], PB1, a0, 0, 0, 0);              \
    a1 = __builtin_amdgcn_mfma_f32_16x16x32_f16(efA[1][1], PB1, a1, 0, 0, 0);              \
    a2 = __builtin_amdgcn_mfma_f32_16x16x32_f16(efA[2][1], PB1, a2, 0, 0, 0);              \
    a3 = __builtin_amdgcn_mfma_f32_16x16x32_f16(efA[3][1], PB1, a3, 0, 0, 0);              \
    half2_t dpk[4][2];                                                                     \
    dpk[0][0] = cvt_pk(a0[0], a0[1]); dpk[0][1] = cvt_pk(a0[2], a0[3]);                    \
    dpk[1][0] = cvt_pk(a1[0], a1[1]); dpk[1][1] = cvt_pk(a1[2], a1[3]);                    \
    dpk[2][0] = cvt_pk(a2[0], a2[1]); dpk[2][1] = cvt_pk(a2[2], a2[3]);                    \
    dpk[3][0] = cvt_pk(a3[0], a3[1]); dpk[3][1] = cvt_pk(a3[2], a3[3]);                    \
    half2_t* wwp0 = (half2_t*)&NB0;                                                        \
    half2_t* wwp1 = (half2_t*)&NB1;                                                        \
    _Pragma("unroll") for (int kf = 0; kf < 2; ++kf) {                                     \
      half2_t* wp = kf ? wwp1 : wwp0;                                                      \
      _Pragma("unroll") for (int p = 0; p < 2; ++p) {                                      \
        const unsigned Xu = __builtin_bit_cast(unsigned, dpk[2 * kf][p]);                  \
        const unsigned Yu = __builtin_bit_cast(unsigned, dpk[2 * kf + 1][p]);              \
        uint2_t r1 = __builtin_amdgcn_permlane32_swap(Xu, Yu, false, false);               \
        uint2_t r2 = __builtin_amdgcn_permlane16_swap(r1[0], r1[1], false, false);         \
        wp[p] = __builtin_bit_cast(half2_t, r2[0]);                                        \
        wp[2 + p] = __builtin_bit_cast(half2_t, r2[1]);                                    \
      }                                                                                    \
    }                                                                                      \
  }

#define MSTEP(GC0, GC1, IT)                                                                \
  {                                                                                        \
    _Pragma("unroll") for (int tile = 0; tile < 4; ++tile) {                               \
      half8_t nb0, nb1;                                                                    \
      MCRF_CORE(pb[tile][0], pb[tile][1], nb0, nb1)                                        \
      pb[tile][0] = nb0 * GC0;                                                             \
      pb[tile][1] = nb1 * GC1;                                                             \
    }                                                                                      \
    if (((IT) & 15) == 15) {                                                               \
      half8_t m8 = __builtin_elementwise_max(pb[0][0], pb[0][1]);                          \
      m8 = __builtin_elementwise_max(m8, __builtin_elementwise_max(pb[1][0], pb[1][1]));   \
      m8 = __builtin_elementwise_max(m8, __builtin_elementwise_max(pb[2][0], pb[2][1]));   \
      m8 = __builtin_elementwise_max(m8, __builtin_elementwise_max(pb[3][0], pb[3][1]));   \
      float mm = (float)m8[0];                                                             \
      _Pragma("unroll") for (int i = 1; i < 8; ++i) mm = fmaxf(mm, (float)m8[i]);          \
      mm = quad_max4(mm);                                                                  \
      mm = fmaxf(mm, __shfl_xor(mm, 1, 64));                                               \
      mm = fmaxf(mm, __shfl_xor(mm, 2, 64));                                               \
      mm = fmaxf(mm, __shfl_xor(mm, 4, 64));                                               \
      mm = fmaxf(mm, __shfl_xor(mm, 8, 64));                                               \
      lz2 += __builtin_amdgcn_logf(mm);                                                    \
      const half8_t rc8 = h8bc(__builtin_amdgcn_rcpf(mm));                                 \
      _Pragma("unroll") for (int tile = 0; tile < 4; ++tile) {                             \
        pb[tile][0] *= rc8;                                                                \
        pb[tile][1] *= rc8;                                                                \
      }                                                                                    \
    }                                                                                      \
  }

  // 4-deep prefetch ring over g_t rows
  half8_t pre0[4], pre1[4];
#pragma unroll
  for (int j = 0; j < 4; ++j) {
    const size_t tt = (size_t)(t0 + j) * 8192;
    pre0[j] = *(const half8_t*)(exb + tt + quad * 8);
    pre1[j] = *(const half8_t*)(exb + tt + 32 + quad * 8);
  }
  int it = 0;
  const int full4 = nsteps >> 2;
  for (int grp = 0; grp < full4; ++grp) {
#pragma unroll
    for (int j = 0; j < 4; ++j) {
      const half8_t gc0 = pre0[j], gc1 = pre1[j];
      int tf = t0 + it + 4;
      tf = tf > 1023 ? 1023 : tf;
      const size_t tt = (size_t)tf * 8192;
      pre0[j] = *(const half8_t*)(exb + tt + quad * 8);
      pre1[j] = *(const half8_t*)(exb + tt + 32 + quad * 8);
      MSTEP(gc0, gc1, it)
      ++it;
    }
  }
  for (; it < nsteps; ++it) {  // tail (s==15: 3 steps)
    const size_t tt = (size_t)(t0 + it) * 8192;
    const half8_t gc0 = *(const half8_t*)(exb + tt + quad * 8);
    const half8_t gc1 = *(const half8_t*)(exb + tt + 32 + quad * 8);
    MSTEP(gc0, gc1, it)
  }
#undef MSTEP
#undef MCRF_CORE

  // store N in P-row-major: Nbuf[b][s][col][k] = pb[tile][kf][i]
  _Float16* nb = Nbuf + ((size_t)b * 16 + s) * 4096;
#pragma unroll
  for (int tile = 0; tile < 4; ++tile) {
    const int col = tile * 16 + n16;
#pragma unroll
    for (int kf = 0; kf < 2; ++kf)
      *(half8_t*)(nb + (size_t)col * 64 + kf * 32 + quad * 8) = pb[tile][kf];
  }
  if (lane == 0) lzbuf[b * 16 + s] = lz2;
}

// ---------------------------------------------------------------- merge: w <- P_s w, then alpha0 dot
__global__ __launch_bounds__(64) void merge_kernel(const _Float16* __restrict__ Nbuf,
                                                   const float* __restrict__ lzbuf,
                                                   const float* __restrict__ em,
                                                   const float* __restrict__ start_trans,
                                                   const float* __restrict__ end_trans,
                                                   float* __restrict__ denom) {
  const int b = blockIdx.x, m = threadIdx.x;
  __shared__ float w[64];
  float L2 = 0.f;
  w[m] = fast_exp(end_trans[m]);
  for (int s = 15; s >= 0; --s) {
    lds_fence();
    const _Float16* row = Nbuf + (((size_t)b * 16 + s) * 64 + m) * 64;
    float acc = 0.f;
#pragma unroll
    for (int kf = 0; kf < 8; ++kf) {
      const half8_t rv = *(const half8_t*)(row + kf * 8);
#pragma unroll
      for (int i = 0; i < 8; ++i) acc += (float)rv[i] * w[kf * 8 + i];
    }
    float mx = acc;
#pragma unroll
    for (int off = 32; off > 0; off >>= 1) mx = fmaxf(mx, __shfl_xor(mx, off, 64));
    L2 += __builtin_amdgcn_logf(mx) + lzbuf[b * 16 + s];
    const float inv = __builtin_amdgcn_rcpf(mx);
    lds_fence();
    w[m] = acc * inv;
  }
  lds_fence();
  const float sv = start_trans[m] + em[(size_t)b * NTAG + m];  // t=0 row
  float m0 = sv;
#pragma unroll
  for (int off = 32; off > 0; off >>= 1) m0 = fmaxf(m0, __shfl_xor(m0, off, 64));
  float z = fast_exp(sv - m0) * w[m];
#pragma unroll
  for (int off = 32; off > 0; off >>= 1) z += __shfl_xor(z, off, 64);
  if (m == 0)
    denom[b] = m0 + 0.693147180559945f * (L2 + 6138.0f + __builtin_amdgcn_logf(z));
}

// ---------------------------------------------------------------- final: reduce (denom - num)
__global__ __launch_bounds__(128) void final_kernel(const float* __restrict__ denom,
                                                    const float* __restrict__ num,
                                                    float* __restrict__ out) {
  const int tid = threadIdx.x;
  float v = denom[tid] - num[tid];
#pragma unroll
  for (int off = 32; off > 0; off >>= 1) v += __shfl_xor(v, off, 64);
  __shared__ float red[2];
  if ((tid & 63) == 0) red[tid >> 6] = v;
  __syncthreads();
  if (tid == 0) out[0] = red[0] + red[1];
}

extern "C" void kernel_launch(void* const* d_in, const int* in_sizes, int n_in,
                              void* d_out, int out_size, void* d_ws, size_t ws_size,
                              hipStream_t stream) {
  const int* kmers = (const int*)d_in[0];
  const int* tags = (const int*)d_in[1];
  const float* emb = (const float*)d_in[2];
  const float* w_ih_f = (const float*)d_in[3];
  const float* w_hh_f = (const float*)d_in[4];
  const float* b_ih_f = (const float*)d_in[5];
  const float* b_hh_f = (const float*)d_in[6];
  const float* w_ih_b = (const float*)d_in[7];
  const float* w_hh_b = (const float*)d_in[8];
  const float* b_ih_b = (const float*)d_in[9];
  const float* b_hh_b = (const float*)d_in[10];
  const float* w_proj = (const float*)d_in[11];
  const float* b_proj = (const float*)d_in[12];
  const float* start_trans = (const float*)d_in[13];
  const float* end_trans = (const float*)d_in[14];
  const float* trans = (const float*)d_in[15];

  char* ws = (char*)d_ws;
  half4_t* x = (half4_t*)ws;                       // [0, 33.5M); em aliases after xg done
  _Float16* h_cat = (_Float16*)(ws + 33554432);    // [33.5M, 100.7M)
  float* em = (float*)ws;
  float* out = (float*)d_out;
  // post-emis overlays of the dead h_cat region (path-independent):
  _Float16* Nbuf = (_Float16*)(ws + 33554432);            // 16.8 MB
  float* lzbuf = (float*)(ws + 33554432 + 16777216);      // 8 KB
  float* denom = (float*)(ws + 33554432 + 16785408);      // 512 B
  float* num = (float*)(ws + 33554432 + 16785920);        // 512 B

  const bool fused = ws_size >= 235078656ull;
  if (fused) {
    const int Tseg = 256;
    _Float16* buf0 = (_Float16*)(ws + 100663296);              // 64 MB
    _Float16* buf1 = (_Float16*)(ws + 100663296 + 67108864);   // 64 MB
    _Float16* expem = (_Float16*)(ws + 100663296);             // aliases buf0 (dead after lstm)
    _Float16* h_state = (_Float16*)(ws + 100663296 + 134217728);
    float* c_state = (float*)(ws + 100663296 + 134217728 + 65536);

    hipLaunchKernelGGL(init_kernel, dim3(48), dim3(256), 0, stream, (float4_t*)h_state);
    hipLaunchKernelGGL(embed_kernel, dim3(16384), dim3(256), 0, stream, kmers, emb, x);
    hipLaunchKernelGGL(xg_kernel, dim3(Tseg), dim3(512), 0, stream, (const _Float16*)x,
                       w_ih_f, b_ih_f, b_hh_f, w_ih_b, b_ih_b, b_hh_b, buf0, 0, Tseg);
    for (int s = 0; s < 3; ++s) {
      _Float16* rd = (s & 1) ? buf1 : buf0;
      _Float16* wr = (s & 1) ? buf0 : buf1;
      hipLaunchKernelGGL(lstm_xg_kernel, dim3(16 + Tseg), dim3(512), 0, stream,
                         (const _Float16*)rd, wr, (const _Float16*)x, w_hh_f, w_hh_b,
                         w_ih_f, b_ih_f, b_hh_f, w_ih_b, b_ih_b, b_hh_b,
                         h_cat, h_state, c_state, s, s + 1, Tseg);
    }
    hipLaunchKernelGGL(lstm_xg_kernel, dim3(16), dim3(512), 0, stream,
                       (const _Float16*)buf1, buf0, (const _Float16*)x, w_hh_f, w_hh_b,
                       w_ih_f, b_ih_f, b_hh_f, w_ih_b, b_ih_b, b_hh_b,
                       h_cat, h_state, c_state, 3, 0, Tseg);
    hipLaunchKernelGGL(emis_kernel, dim3(2048), dim3(256), 0, stream, h_cat, w_proj, b_proj, em,
                       expem);
    hipLaunchKernelGGL(mcrf_kernel, dim3(2176), dim3(64), 0, stream, em,
                       (const _Float16*)expem, trans, tags, start_trans, end_trans, Nbuf, lzbuf,
                       num);
    hipLaunchKernelGGL(merge_kernel, dim3(128), dim3(64), 0, stream, (const _Float16*)Nbuf,
                       lzbuf, em, start_trans, end_trans, denom);
    hipLaunchKernelGGL(final_kernel, dim3(1), dim3(128), 0, stream, denom, num, out);
  } else {
    int nseg;
    if (ws_size >= 167969792ull) nseg = 4;
    else if (ws_size >= 134415360ull) nseg = 8;
    else nseg = 16;
    const int Tseg = TT / nseg;
    const size_t xg_bytes = 268435456ull / (size_t)nseg;
    _Float16* xgbuf = (_Float16*)(ws + 100663296);
    _Float16* expem = (_Float16*)(ws + 100663296);
    _Float16* h_state = (_Float16*)(ws + 100663296 + xg_bytes);
    float* c_state = (float*)(ws + 100663296 + xg_bytes + 65536);

    hipLaunchKernelGGL(init_kernel, dim3(48), dim3(256), 0, stream, (float4_t*)h_state);
    hipLaunchKernelGGL(embed_kernel, dim3(16384), dim3(256), 0, stream, kmers, emb, x);
    for (int s = 0; s < nseg; ++s) {
      hipLaunchKernelGGL(xg_kernel, dim3(Tseg), dim3(512), 0, stream, (const _Float16*)x,
                         w_ih_f, b_ih_f, b_hh_f, w_ih_b, b_ih_b, b_hh_b, xgbuf, s, Tseg);
      hipLaunchKernelGGL(lstm_xg_kernel, dim3(16), dim3(512), 0, stream,
                         (const _Float16*)xgbuf, xgbuf, (const _Float16*)x, w_hh_f, w_hh_b,
                         w_ih_f, b_ih_f, b_hh_f, w_ih_b, b_ih_b, b_hh_b,
                         h_cat, h_state, c_state, s, s, Tseg);
    }
    hipLaunchKernelGGL(emis_kernel, dim3(2048), dim3(256), 0, stream, h_cat, w_proj, b_proj, em,
                       expem);
    hipLaunchKernelGGL(mcrf_kernel, dim3(2176), dim3(64), 0, stream, em,
                       (const _Float16*)expem, trans, tags, start_trans, end_trans, Nbuf, lzbuf,
                       num);
    hipLaunchKernelGGL(merge_kernel, dim3(128), dim3(64), 0, stream, (const _Float16*)Nbuf,
                       lzbuf, em, start_trans, end_trans, denom);
    hipLaunchKernelGGL(final_kernel, dim3(1), dim3(128), 0, stream, denom, num, out);
  }
}